// Round 3
// baseline (691.979 us; speedup 1.0000x reference)
//
#include <hip/hip_runtime.h>
#include <hip/hip_bf16.h>
#include <stdint.h>

#define N_  6144
#define T_  3072
#define D_  128
#define H_  4
#define HD_ 512

typedef float f32x4 __attribute__((ext_vector_type(4)));
typedef short s16x8 __attribute__((ext_vector_type(8)));

static __device__ __forceinline__ short f2bf(float f) {
  union { __hip_bfloat16 b; short s; } u;
  u.b = __float2bfloat16(f);
  return u.s;
}

// ---------------- adj (int32 0/1) -> bitmask ----------------
__global__ __launch_bounds__(256) void bits_kernel(const int* __restrict__ adj,
                                                   unsigned long long* __restrict__ bits,
                                                   int nwords) {
  int lane = threadIdx.x & 63;
  int gw = (blockIdx.x * blockDim.x + threadIdx.x) >> 6;
  int nw = (gridDim.x * blockDim.x) >> 6;
  for (int w = gw; w < nwords; w += nw) {
    int v = adj[(long)w * 64 + lane];
    unsigned long long b = __ballot(v != 0);
    if (lane == 0) bits[w] = b;
  }
}

// ---------------- fp32 -> bf16 (same layout) ----------------
__global__ __launch_bounds__(256) void cvt_kernel(const float* __restrict__ in,
                                                  short* __restrict__ out, int count4) {
  int i = blockIdx.x * blockDim.x + threadIdx.x;
  if (i < count4) {
    float4 v = *(const float4*)(in + (long)i * 4);
    short4 o;
    o.x = f2bf(v.x); o.y = f2bf(v.y); o.z = f2bf(v.z); o.w = f2bf(v.w);
    *(short4*)(out + (long)i * 4) = o;
  }
}

// ---------------- fp32 [R][C] -> bf16 [C][R] (batched) ----------------
__global__ __launch_bounds__(256) void tcvt_kernel(const float* __restrict__ in,
                                                   short* __restrict__ out,
                                                   int R, int C, long sIn, long sOut) {
  __shared__ float t[32][33];
  in += (long)blockIdx.z * sIn;
  out += (long)blockIdx.z * sOut;
  int c0 = blockIdx.x * 32, r0 = blockIdx.y * 32;
  int tx = threadIdx.x, ty = threadIdx.y;   // block (32,8)
#pragma unroll
  for (int i = 0; i < 4; ++i)
    t[ty + 8 * i][tx] = in[(long)(r0 + ty + 8 * i) * C + c0 + tx];
  __syncthreads();
#pragma unroll
  for (int i = 0; i < 4; ++i)
    out[(long)(c0 + ty + 8 * i) * R + r0 + tx] = f2bf(t[tx][ty + 8 * i]);
}

// ---------------- u_s[h][d] = sum_e W[h][d][e]*a_src[h][e] ----------------
__global__ void headvec_kernel(const float* __restrict__ W, const float* __restrict__ a_s,
                               const float* __restrict__ a_d, float* __restrict__ u_s,
                               float* __restrict__ u_d) {
  int h = blockIdx.x, d = threadIdx.x;
  const float* wr = W + ((long)h * D_ + d) * D_;
  const float* as = a_s + h * D_;
  const float* ad = a_d + h * D_;
  float s = 0.f, t = 0.f;
#pragma unroll 8
  for (int e = 0; e < D_; ++e) { s += wr[e] * as[e]; t += wr[e] * ad[e]; }
  u_s[h * D_ + d] = s;
  u_d[h * D_ + d] = t;
}

// ---------------- f_s/f_d (pre-scaled by log2e) ----------------
__global__ __launch_bounds__(256) void fvec_kernel(const float* __restrict__ x,
                                                   const float* __restrict__ u_s,
                                                   const float* __restrict__ u_d,
                                                   float* __restrict__ fsA,
                                                   float* __restrict__ fdA,
                                                   int n) {
  __shared__ float usl[128], udl[128];
  long idx = (long)blockIdx.x * 256 + threadIdx.x;
  int h = (int)(idx / n), i = (int)(idx % n);
  if (threadIdx.x < 128) {
    usl[threadIdx.x] = u_s[h * D_ + threadIdx.x];
    udl[threadIdx.x] = u_d[h * D_ + threadIdx.x];
  }
  __syncthreads();
  const float4* xr = (const float4*)(x + (long)i * D_);
  float s = 0.f, t = 0.f;
#pragma unroll 8
  for (int e4 = 0; e4 < 32; ++e4) {
    float4 xv = xr[e4];
    s += xv.x * usl[4 * e4] + xv.y * usl[4 * e4 + 1] + xv.z * usl[4 * e4 + 2] + xv.w * usl[4 * e4 + 3];
    t += xv.x * udl[4 * e4] + xv.y * udl[4 * e4 + 1] + xv.z * udl[4 * e4 + 2] + xv.w * udl[4 * e4 + 3];
  }
  const float L2E = 1.4426950408889634f;
  fsA[idx] = s * L2E;
  fdA[idx] = t * L2E;
}

// ---------------- generic bf16 MFMA GEMM (depth-2 prefetch, 1 barrier/iter) ----
// epi: 0 = bf16 store, 1 = fp32 relu+bias, 2 = bf16 relu+bias transposed, 3 = fp32 plain (+bz*sOut)
__global__ __launch_bounds__(256) void gemm_kernel(const short* __restrict__ A,
                                                   const short* __restrict__ BT,
                                                   int M, int K, int lda, int ldb,
                                                   float* __restrict__ outF, short* __restrict__ outB,
                                                   const float* __restrict__ bias,
                                                   int ldo, int epi,
                                                   long sA, long sBT, long sOut) {
  int bz = blockIdx.z;
  A += bz * sA;
  BT += bz * sBT;
  __shared__ __align__(16) short bs[2][4096];
  int tid = threadIdx.x, w = tid >> 6, l = tid & 63, lm = l & 15, lg = l >> 4;
  int row0 = blockIdx.x * 64 + w * 16;
  int col0 = blockIdx.y * 128;
  const short* arow = A + (long)(row0 + lm) * lda + 8 * lg;
  const short* b0 = BT + (long)(col0 + 16 * (2 * w + 0) + lm) * ldb + 8 * lg;
  const short* b1 = BT + (long)(col0 + 16 * (2 * w + 1) + lm) * ldb + 8 * lg;
  f32x4 acc[8] = {};
  int nt = K / 32;
  int4 pr0[2], pr1[2];
  s16x8 prA[2];
  pr0[0] = *(const int4*)(b0);      pr1[0] = *(const int4*)(b1);      prA[0] = *(const s16x8*)(arow);
  pr0[1] = *(const int4*)(b0 + 32); pr1[1] = *(const int4*)(b1 + 32); prA[1] = *(const s16x8*)(arow + 32);
  for (int kt = 0; kt < nt; ++kt) {
    int sl = kt & 1;
    ((int4*)bs[sl])[(2 * w + 0) * 64 + l] = pr0[sl];
    ((int4*)bs[sl])[(2 * w + 1) * 64 + l] = pr1[sl];
    s16x8 af = prA[sl];
    int kn = (kt + 2 < nt ? kt + 2 : kt) * 32;
    pr0[sl] = *(const int4*)(b0 + kn);
    pr1[sl] = *(const int4*)(b1 + kn);
    prA[sl] = *(const s16x8*)(arow + kn);
    __syncthreads();
#pragma unroll
    for (int f = 0; f < 8; ++f) {
      s16x8 bf = *(const s16x8*)(bs[sl] + f * 512 + l * 8);
      acc[f] = __builtin_amdgcn_mfma_f32_16x16x32_bf16(af, bf, acc[f], 0, 0, 0);
    }
  }
#pragma unroll
  for (int f = 0; f < 8; ++f) {
    int col = col0 + 16 * f + lm;
#pragma unroll
    for (int r = 0; r < 4; ++r) {
      int row = row0 + 4 * lg + r;
      float v = acc[f][r];
      if (epi == 0) {
        outB[bz * sOut + (long)row * ldo + col] = f2bf(v);
      } else if (epi == 1) {
        v += bias[col]; v = v > 0.f ? v : 0.f;
        outF[(long)row * ldo + col] = v;
      } else if (epi == 2) {
        v += bias[col]; v = v > 0.f ? v : 0.f;
        outB[(long)col * ldo + row] = f2bf(v);
      } else {
        outF[bz * sOut + (long)row * ldo + col] = v;
      }
    }
  }
}

// ---------------- fused masked-softmax attention, 128 rows/block, k-split ----
// grid (n/128, H, S), block 256. fp32 partial acc [h][rb][s][128][128] + partial Z [...][128].
__global__ __launch_bounds__(256) void attn_kernel(const short* __restrict__ WhT,
                                                   const unsigned char* __restrict__ bits,
                                                   const float* __restrict__ fsA,
                                                   const float* __restrict__ fdA,
                                                   float* __restrict__ pacc,
                                                   float* __restrict__ pz,
                                                   int n, int S) {
  int h = blockIdx.y, sp = blockIdx.z;
  int RB = gridDim.x;
  int klen = n / S, k0 = sp * klen;
  const short* whT = WhT + (long)h * D_ * n;
  const float* fa = fdA + (long)h * n;
  __shared__ __align__(16) short bs[2][4096];
  int tid = threadIdx.x, w = tid >> 6, l = tid & 63, lm = l & 15, lg = l >> 4;
  int i0 = blockIdx.x * 128;
  int irow0 = i0 + w * 16 + lm;
  int irow1 = irow0 + 64;
  float fsAi0 = fsA[(long)h * n + irow0];
  float fsAi1 = fsA[(long)h * n + irow1];
  const unsigned char* brow0 = bits + (long)irow0 * (n >> 3);
  const unsigned char* brow1 = bits + (long)irow1 * (n >> 3);
  const short* s0 = whT + (long)(16 * (2 * w + 0) + lm) * n + 8 * lg + k0;
  const short* s1 = whT + (long)(16 * (2 * w + 1) + lm) * n + 8 * lg + k0;
  f32x4 acc0[8] = {}, acc1[8] = {};
  float z0 = 0.f, z1 = 0.f;
  int nt = klen / 32;
  int4 pr0[2], pr1[2];
  pr0[0] = *(const int4*)(s0);      pr1[0] = *(const int4*)(s1);
  pr0[1] = *(const int4*)(s0 + 32); pr1[1] = *(const int4*)(s1 + 32);
  float favC[8];
  unsigned mbC0, mbC1;
  *(float4*)(favC) = *(const float4*)(fa + k0 + 8 * lg);
  *(float4*)(favC + 4) = *(const float4*)(fa + k0 + 8 * lg + 4);
  mbC0 = brow0[(k0 + 8 * lg) >> 3];
  mbC1 = brow1[(k0 + 8 * lg) >> 3];
  for (int kt = 0; kt < nt; ++kt) {
    int sl = kt & 1;
    ((int4*)bs[sl])[(2 * w + 0) * 64 + l] = pr0[sl];
    ((int4*)bs[sl])[(2 * w + 1) * 64 + l] = pr1[sl];
    int kn2 = (kt + 2 < nt ? kt + 2 : kt) * 32;
    pr0[sl] = *(const int4*)(s0 + kn2);
    pr1[sl] = *(const int4*)(s1 + kn2);
    int kn1 = k0 + (kt + 1 < nt ? kt + 1 : kt) * 32;
    float favN[8];
    unsigned mbN0, mbN1;
    *(float4*)(favN) = *(const float4*)(fa + kn1 + 8 * lg);
    *(float4*)(favN + 4) = *(const float4*)(fa + kn1 + 8 * lg + 4);
    mbN0 = brow0[(kn1 + 8 * lg) >> 3];
    mbN1 = brow1[(kn1 + 8 * lg) >> 3];
    union { s16x8 v; unsigned u[4]; } af0, af1;
#pragma unroll
    for (int jj = 0; jj < 4; ++jj) {
      float x0 = favC[2 * jj], x1 = favC[2 * jj + 1];
      float ua = fsAi0 + x0, ub = fsAi0 + x1;
      ua = ((mbC0 >> (2 * jj)) & 1u) ? ua : -1e30f;
      ub = ((mbC0 >> (2 * jj + 1)) & 1u) ? ub : -1e30f;
      float pa = __builtin_amdgcn_exp2f(fmaxf(ua, 0.2f * ua));
      float pb = __builtin_amdgcn_exp2f(fmaxf(ub, 0.2f * ub));
      z0 += pa + pb;
      unsigned ba = __float_as_uint(pa) + 0x8000u;
      unsigned bb = __float_as_uint(pb) + 0x8000u;
      af0.u[jj] = __builtin_amdgcn_perm(bb, ba, 0x07060302);
      ua = fsAi1 + x0; ub = fsAi1 + x1;
      ua = ((mbC1 >> (2 * jj)) & 1u) ? ua : -1e30f;
      ub = ((mbC1 >> (2 * jj + 1)) & 1u) ? ub : -1e30f;
      pa = __builtin_amdgcn_exp2f(fmaxf(ua, 0.2f * ua));
      pb = __builtin_amdgcn_exp2f(fmaxf(ub, 0.2f * ub));
      z1 += pa + pb;
      ba = __float_as_uint(pa) + 0x8000u;
      bb = __float_as_uint(pb) + 0x8000u;
      af1.u[jj] = __builtin_amdgcn_perm(bb, ba, 0x07060302);
    }
    __syncthreads();
#pragma unroll
    for (int f = 0; f < 8; ++f) {
      s16x8 bf = *(const s16x8*)(bs[sl] + f * 512 + l * 8);
      acc0[f] = __builtin_amdgcn_mfma_f32_16x16x32_bf16(af0.v, bf, acc0[f], 0, 0, 0);
      acc1[f] = __builtin_amdgcn_mfma_f32_16x16x32_bf16(af1.v, bf, acc1[f], 0, 0, 0);
    }
#pragma unroll
    for (int j = 0; j < 8; ++j) favC[j] = favN[j];
    mbC0 = mbN0; mbC1 = mbN1;
  }
  z0 += __shfl_xor(z0, 16); z0 += __shfl_xor(z0, 32);
  z1 += __shfl_xor(z1, 16); z1 += __shfl_xor(z1, 32);
  long pzb = (((long)h * RB + blockIdx.x) * S + sp) * 128;
  if (l < 16) {
    pz[pzb + w * 16 + lm] = z0;
    pz[pzb + 64 + w * 16 + lm] = z1;
  }
  long pb = (((long)h * RB + blockIdx.x) * S + sp) * 16384;
#pragma unroll
  for (int f = 0; f < 8; ++f) {
#pragma unroll
    for (int r = 0; r < 4; ++r) {
      pacc[pb + (long)(w * 16 + 4 * lg + r) * 128 + 16 * f + lm] = acc0[f][r];
      pacc[pb + (long)(64 + w * 16 + 4 * lg + r) * 128 + 16 * f + lm] = acc1[f][r];
    }
  }
}

// ---------------- combine k-split partials: /Z, elu, write bf16 head-concat ----------------
__global__ __launch_bounds__(256) void attn_combine_kernel(const float* __restrict__ pacc,
                                                           const float* __restrict__ pz,
                                                           short* __restrict__ hcat,
                                                           int n, int S) {
  int h = blockIdx.y, rb = blockIdx.x;
  int RB = gridDim.x;
  long pb = ((long)h * RB + rb) * S * 16384;
  long zb = ((long)h * RB + rb) * S * 128;
  __shared__ float zl[128];
  int tid = threadIdx.x;
  if (tid < 128) {
    float z = 0.f;
    for (int s = 0; s < S; ++s) z += pz[zb + (long)s * 128 + tid];
    zl[tid] = 1.f / z;
  }
  __syncthreads();
  int i0 = rb * 128;
#pragma unroll
  for (int k = 0; k < 16; ++k) {
    int e = tid * 4 + k * 1024;
    int row = e >> 7, col = e & 127;
    f32x4 v = {};
    for (int s = 0; s < S; ++s) v += *(const f32x4*)(pacc + pb + (long)s * 16384 + e);
    float iz = zl[row];
    short4 o;
    float t;
    t = v[0] * iz; o.x = f2bf(t > 0.f ? t : __expf(t) - 1.f);
    t = v[1] * iz; o.y = f2bf(t > 0.f ? t : __expf(t) - 1.f);
    t = v[2] * iz; o.z = f2bf(t > 0.f ? t : __expf(t) - 1.f);
    t = v[3] * iz; o.w = f2bf(t > 0.f ? t : __expf(t) - 1.f);
    *(short4*)(hcat + (long)(i0 + row) * HD_ + h * D_ + col) = o;
  }
}

// ---------------- gated fusion (ctext from Sc partials) + final GEMM + relu ----------------
__global__ __launch_bounds__(256) void fusion_kernel(const float* __restrict__ concept,
                                                     const float* __restrict__ ctextP,
                                                     int Sc, long sCt,
                                                     const short* __restrict__ fusT,
                                                     const float* __restrict__ fus_b,
                                                     float* __restrict__ out) {
  __shared__ __align__(16) short als[64 * 136];
  int tid = threadIdx.x;
  int r0 = blockIdx.x * 64;
#pragma unroll
  for (int it = 0; it < 8; ++it) {
    int e = it * 1024 + tid * 4;
    int r = e >> 7, c = e & 127;
    float4 cv = *(const float4*)(concept + (long)(r0 + r) * D_ + c);
    f32x4 tv = {};
    for (int s = 0; s < Sc; ++s)
      tv += *(const f32x4*)(ctextP + (long)s * sCt + (long)(r0 + r) * D_ + c);
    short4 o;
    {
      float s0 = cv.x + tv[0]; float z = 1.f / (1.f + __expf(-s0)); o.x = f2bf(tv[0] + z * (cv.x - tv[0]));
      s0 = cv.y + tv[1]; z = 1.f / (1.f + __expf(-s0)); o.y = f2bf(tv[1] + z * (cv.y - tv[1]));
      s0 = cv.z + tv[2]; z = 1.f / (1.f + __expf(-s0)); o.z = f2bf(tv[2] + z * (cv.z - tv[2]));
      s0 = cv.w + tv[3]; z = 1.f / (1.f + __expf(-s0)); o.w = f2bf(tv[3] + z * (cv.w - tv[3]));
    }
    *(short4*)(als + (long)r * 136 + c) = o;
  }
  __syncthreads();
  int w = tid >> 6, l = tid & 63, lm = l & 15, lg = l >> 4;
  f32x4 acc[8] = {};
#pragma unroll
  for (int kt = 0; kt < 4; ++kt) {
    int kb = kt * 32;
    s16x8 af = *(const s16x8*)(als + (16 * w + lm) * 136 + kb + 8 * lg);
#pragma unroll
    for (int f = 0; f < 8; ++f) {
      s16x8 bf = *(const s16x8*)(fusT + (long)(16 * f + lm) * D_ + kb + 8 * lg);
      acc[f] = __builtin_amdgcn_mfma_f32_16x16x32_bf16(af, bf, acc[f], 0, 0, 0);
    }
  }
#pragma unroll
  for (int f = 0; f < 8; ++f) {
    int col = 16 * f + lm;
#pragma unroll
    for (int r = 0; r < 4; ++r) {
      float v = acc[f][r] + fus_b[col];
      v = v > 0.f ? v : 0.f;
      out[(long)(r0 + 16 * w + 4 * lg + r) * D_ + col] = v;
    }
  }
}

extern "C" void kernel_launch(void* const* d_in, const int* in_sizes, int n_in,
                              void* d_out, int out_size, void* d_ws, size_t ws_size,
                              hipStream_t stream) {
  (void)in_sizes; (void)n_in; (void)out_size;
  const float* x      = (const float*)d_in[0];
  const int*   adj    = (const int*)d_in[1];
  const float* t_x    = (const float*)d_in[2];
  const int*   t_adj  = (const int*)d_in[3];
  const float* tfidf  = (const float*)d_in[4];
  const float* Wg     = (const float*)d_in[5];
  const float* ag_src = (const float*)d_in[6];
  const float* ag_dst = (const float*)d_in[7];
  const float* fcg_W  = (const float*)d_in[8];
  const float* fcg_b  = (const float*)d_in[9];
  const float* Wt     = (const float*)d_in[10];
  const float* at_src = (const float*)d_in[11];
  const float* at_dst = (const float*)d_in[12];
  const float* fct_W  = (const float*)d_in[13];
  const float* fct_b  = (const float*)d_in[14];
  const float* fus_W  = (const float*)d_in[15];
  const float* fus_b  = (const float*)d_in[16];
  float* out = (float*)d_out;

  char* ws = (char*)d_ws;
  size_t off = 0;
  auto alloc = [&](size_t bytes) -> char* {
    char* p = ws + off;
    off = (off + bytes + 255) & ~(size_t)255;
    return p;
  };
  unsigned long long* bitsG = (unsigned long long*)alloc((size_t)N_ * N_ / 8);
  unsigned long long* bitsT = (unsigned long long*)alloc((size_t)T_ * T_ / 8);
  short* xb     = (short*)alloc((size_t)N_ * D_ * 2);
  short* txb    = (short*)alloc((size_t)T_ * D_ * 2);
  short* WgT    = (short*)alloc((size_t)H_ * D_ * D_ * 2);
  short* WtT    = (short*)alloc((size_t)H_ * D_ * D_ * 2);
  short* fcgT   = (short*)alloc((size_t)HD_ * D_ * 2);
  short* fctT   = (short*)alloc((size_t)HD_ * D_ * 2);
  short* fusT   = (short*)alloc((size_t)D_ * D_ * 2);
  short* tfidfT = (short*)alloc((size_t)N_ * T_ * 2);
  short* WhTg   = (short*)alloc((size_t)H_ * D_ * N_ * 2);
  short* WhTt   = (short*)alloc((size_t)H_ * D_ * T_ * 2);
  float* usG = (float*)alloc(H_ * D_ * 4);
  float* udG = (float*)alloc(H_ * D_ * 4);
  float* usT = (float*)alloc(H_ * D_ * 4);
  float* udT = (float*)alloc(H_ * D_ * 4);
  float* fsAg = (float*)alloc((size_t)H_ * N_ * 4);
  float* fdAg = (float*)alloc((size_t)H_ * N_ * 4);
  float* fsAt = (float*)alloc((size_t)H_ * T_ * 4);
  float* fdAt = (float*)alloc((size_t)H_ * T_ * 4);
  short* hcatG = (short*)alloc((size_t)N_ * HD_ * 2);
  short* hcatT = (short*)alloc((size_t)T_ * HD_ * 2);
  short* gatT  = (short*)alloc((size_t)D_ * T_ * 2);
  float* conceptF = (float*)alloc((size_t)N_ * D_ * 4);

  const int RBg = N_ / 128, RBt = T_ / 128;
  const size_t paccG1 = (size_t)H_ * RBg * 16384 * 4, pzG1 = (size_t)H_ * RBg * 128 * 4;
  const size_t paccT1 = (size_t)H_ * RBt * 16384 * 4, pzT1 = (size_t)H_ * RBt * 128 * 4;
  const size_t ctp1 = (size_t)N_ * D_ * 4;
  size_t rem = (ws_size > off + (1 << 20)) ? (ws_size - off - (1 << 20)) : 0;
  int Sg = 1, St = 1, Sc = 1;
  if (rem >= 4 * (paccG1 + pzG1) + 4 * (paccT1 + pzT1) + 4 * ctp1) { Sg = 4; St = 4; Sc = 4; }
  else if (rem >= 4 * (paccG1 + pzG1) + 4 * (paccT1 + pzT1) + ctp1) { Sg = 4; St = 4; }
  else if (rem >= 2 * (paccG1 + pzG1) + 2 * (paccT1 + pzT1) + ctp1) { Sg = 2; St = 2; }
  float* paccG = (float*)alloc(Sg * paccG1);
  float* pzG   = (float*)alloc(Sg * pzG1);
  float* paccT = (float*)alloc(St * paccT1);
  float* pzT   = (float*)alloc(St * pzT1);
  float* ctextP = (float*)alloc(Sc * ctp1);

  // --- prep ---
  bits_kernel<<<dim3(1024), dim3(256), 0, stream>>>(adj, bitsG, N_ * N_ / 64);
  bits_kernel<<<dim3(512), dim3(256), 0, stream>>>(t_adj, bitsT, T_ * T_ / 64);
  cvt_kernel<<<dim3(N_ * D_ / 1024), dim3(256), 0, stream>>>(x, xb, N_ * D_ / 4);
  cvt_kernel<<<dim3(T_ * D_ / 1024), dim3(256), 0, stream>>>(t_x, txb, T_ * D_ / 4);
  tcvt_kernel<<<dim3(4, 4, 4), dim3(32, 8), 0, stream>>>(Wg, WgT, D_, D_, (long)D_ * D_, (long)D_ * D_);
  tcvt_kernel<<<dim3(4, 4, 4), dim3(32, 8), 0, stream>>>(Wt, WtT, D_, D_, (long)D_ * D_, (long)D_ * D_);
  tcvt_kernel<<<dim3(4, 16, 1), dim3(32, 8), 0, stream>>>(fcg_W, fcgT, HD_, D_, 0, 0);
  tcvt_kernel<<<dim3(4, 16, 1), dim3(32, 8), 0, stream>>>(fct_W, fctT, HD_, D_, 0, 0);
  tcvt_kernel<<<dim3(4, 4, 1), dim3(32, 8), 0, stream>>>(fus_W, fusT, D_, D_, 0, 0);
  tcvt_kernel<<<dim3(N_ / 32, T_ / 32, 1), dim3(32, 8), 0, stream>>>(tfidf, tfidfT, T_, N_, 0, 0);
  headvec_kernel<<<dim3(H_), dim3(128), 0, stream>>>(Wg, ag_src, ag_dst, usG, udG);
  headvec_kernel<<<dim3(H_), dim3(128), 0, stream>>>(Wt, at_src, at_dst, usT, udT);
  fvec_kernel<<<dim3(H_ * N_ / 256), dim3(256), 0, stream>>>(x, usG, udG, fsAg, fdAg, N_);
  fvec_kernel<<<dim3(H_ * T_ / 256), dim3(256), 0, stream>>>(t_x, usT, udT, fsAt, fdAt, T_);

  // --- WhT = W^T x^T  (per head), bf16 out [H][128][n] ---
  gemm_kernel<<<dim3(2, N_ / 128, H_), dim3(256), 0, stream>>>(
      WgT, xb, D_, D_, D_, D_, nullptr, WhTg, nullptr, N_, 0,
      (long)D_ * D_, 0, (long)D_ * N_);
  gemm_kernel<<<dim3(2, T_ / 128, H_), dim3(256), 0, stream>>>(
      WtT, txb, D_, D_, D_, D_, nullptr, WhTt, nullptr, T_, 0,
      (long)D_ * D_, 0, (long)D_ * T_);

  // --- attention (k-split partials + combine) ---
  attn_kernel<<<dim3(RBg, H_, Sg), dim3(256), 0, stream>>>(
      WhTg, (const unsigned char*)bitsG, fsAg, fdAg, paccG, pzG, N_, Sg);
  attn_combine_kernel<<<dim3(RBg, H_), dim3(256), 0, stream>>>(paccG, pzG, hcatG, N_, Sg);
  attn_kernel<<<dim3(RBt, H_, St), dim3(256), 0, stream>>>(
      WhTt, (const unsigned char*)bitsT, fsAt, fdAt, paccT, pzT, T_, St);
  attn_combine_kernel<<<dim3(RBt, H_), dim3(256), 0, stream>>>(paccT, pzT, hcatT, T_, St);

  // --- head-concat FC: concept (fp32) and gat_text (bf16, transposed) ---
  gemm_kernel<<<dim3(N_ / 64, 1, 1), dim3(256), 0, stream>>>(
      hcatG, fcgT, N_, HD_, HD_, HD_, conceptF, nullptr, fcg_b, D_, 1, 0, 0, 0);
  gemm_kernel<<<dim3(T_ / 64, 1, 1), dim3(256), 0, stream>>>(
      hcatT, fctT, T_, HD_, HD_, HD_, nullptr, gatT, fct_b, T_, 2, 0, 0, 0);

  // --- c_text partials = tfidf^T @ gat_text (k-split Sc) ---
  gemm_kernel<<<dim3(N_ / 64, 1, Sc), dim3(256), 0, stream>>>(
      tfidfT, gatT, N_, T_ / Sc, T_, T_, ctextP, nullptr, nullptr, D_, 3,
      (long)(T_ / Sc), (long)(T_ / Sc), (long)N_ * D_);

  // --- gated fusion + final linear + relu ---
  fusion_kernel<<<dim3(N_ / 64), dim3(256), 0, stream>>>(conceptF, ctextP, Sc, (long)N_ * D_,
                                                         fusT, fus_b, out);
}